// Round 5
// baseline (206.830 us; speedup 1.0000x reference)
//
#include <hip/hip_runtime.h>
#include <hip/hip_bf16.h>
#include <math.h>

// Router: logits = x@W + b ; softmax; top-2 -> (idx-as-float, gate)
// x: [16384, 2048] f32, W: [2048, 64] f32, b: [64] f32
// out f32: [ntok*2] indices, then [ntok*2] gates.
//
// R5 theory: rounds 3-4 plateaued at ~65 us because x was fetched in 128-B
// per-row granules across ~16k live rows -> HBM row-buffer thrash (~2 TB/s).
// Fix: K split across blocks. Each block = 32 tokens x 512 k; DMA fetches
// each row's 2-KB slice fully contiguously (2 x 1KB global_load_lds).
// bf16 hi/lo split MFMA (3 products). Partials reduced by a second kernel.

#define DIM 2048
#define NE 64
#define RSTRIDE 2064  // 512 floats (2 KB) + 16 B pad -> conflict-free b128

typedef __attribute__((ext_vector_type(8))) short short8;
typedef __attribute__((ext_vector_type(4))) float floatx4;

__device__ __forceinline__ short bf16bits(float v) {
  __hip_bfloat16 h = __float2bfloat16(v);
  return *(short*)&h;
}
__device__ __forceinline__ float bf16tof(short s) {
  union { unsigned int u; float f; } c;
  c.u = ((unsigned int)(unsigned short)s) << 16;
  return c.f;
}

// ---- W fragment prep: wf[sg(64)][n(4)][plane(2)][lane(64)] = short8 ----
// B-frag 16x16x32: lane l holds B[k = sg*32 + (l>>4)*8 + j][e = n*16 + (l&15)]
__global__ void wprep_kernel(const float* __restrict__ W, short8* __restrict__ wf) {
  const int s = blockIdx.x >> 2, n = blockIdx.x & 3, l = threadIdx.x;
  const int d0 = s * 32 + (l >> 4) * 8;
  const int e = n * 16 + (l & 15);
  short8 vh, vl;
#pragma unroll
  for (int j = 0; j < 8; ++j) {
    float v = W[(size_t)(d0 + j) * NE + e];
    short h = bf16bits(v);
    vh[j] = h;
    vl[j] = bf16bits(v - bf16tof(h));
  }
  wf[(size_t)((s * 4 + n) * 2 + 0) * 64 + l] = vh;
  wf[(size_t)((s * 4 + n) * 2 + 1) * 64 + l] = vl;
}

__device__ __forceinline__ void async_copy16(const float* g, void* lds) {
  __builtin_amdgcn_global_load_lds(
      (const __attribute__((address_space(1))) unsigned int*)g,
      (__attribute__((address_space(3))) unsigned int*)lds, 16, 0, 0);
}

// ---- kernel 1: partial GEMM. block (g,s): tokens [g*32,+32), k [s*512,+512)
__global__ __launch_bounds__(256, 2) void router_gemm(
    const float* __restrict__ x, const short8* __restrict__ wf,
    float* __restrict__ part) {
  __shared__ alignas(16) char smem[32 * RSTRIDE];  // 66048 B
  const int tid = threadIdx.x, lane = tid & 63, kq = tid >> 6;
  const int g = lane & 15, r4 = lane >> 4;
  const int gblk = blockIdx.x >> 2, s = blockIdx.x & 3;
  const int tok0 = gblk * 32;

  // whole-block stage: wave kq fetches rows [kq*8, kq*8+8), 2 KB each,
  // as 2 contiguous 1-KB DMA instructions per row (HBM-friendly bursts).
  {
    const float* xb = x + (size_t)tok0 * DIM + s * 512;
#pragma unroll
    for (int r = 0; r < 8; ++r) {
      const int row = kq * 8 + r;
      const float* rp = xb + (size_t)row * DIM;
      char* dst = smem + row * RSTRIDE;
      async_copy16(rp + lane * 4, dst);
      async_copy16(rp + 256 + lane * 4, dst + 1024);
    }
  }

  floatx4 acc[2][4];
#pragma unroll
  for (int mt = 0; mt < 2; ++mt)
#pragma unroll
    for (int n = 0; n < 4; ++n) acc[mt][n] = (floatx4){0.f, 0.f, 0.f, 0.f};

  __syncthreads();  // compiler emits vmcnt(0) drain: whole tile resident

  // wave kq computes k-range [kq*128, +128) of the block's 512-k slice
#pragma unroll
  for (int step = 0; step < 4; ++step) {
    const int sg = s * 16 + kq * 4 + step;  // global 32-k step index
    const short8* wp = wf + (size_t)sg * 8 * 64;
    short8 Wh[4], Wl[4];
#pragma unroll
    for (int n = 0; n < 4; ++n) {
      Wh[n] = wp[(n * 2 + 0) * 64 + lane];
      Wl[n] = wp[(n * 2 + 1) * 64 + lane];
    }
    const int colb = kq * 512 + step * 128 + r4 * 32;  // byte offset in row
#pragma unroll
    for (int mt = 0; mt < 2; ++mt) {
      const int row = mt * 16 + g;  // A: m = lane&15 (token)
      const float* ap = (const float*)(smem + row * RSTRIDE + colb);
      floatx4 a0 = *(const floatx4*)ap;
      floatx4 a1 = *(const floatx4*)(ap + 4);
      short8 Ah, Al;
#pragma unroll
      for (int j = 0; j < 4; ++j) {
        short h = bf16bits(a0[j]);
        Ah[j] = h; Al[j] = bf16bits(a0[j] - bf16tof(h));
      }
#pragma unroll
      for (int j = 0; j < 4; ++j) {
        short h = bf16bits(a1[j]);
        Ah[4 + j] = h; Al[4 + j] = bf16bits(a1[j] - bf16tof(h));
      }
#pragma unroll
      for (int n = 0; n < 4; ++n) {
        acc[mt][n] = __builtin_amdgcn_mfma_f32_16x16x32_bf16(Ah, Wh[n], acc[mt][n], 0, 0, 0);
        acc[mt][n] = __builtin_amdgcn_mfma_f32_16x16x32_bf16(Ah, Wl[n], acc[mt][n], 0, 0, 0);
        acc[mt][n] = __builtin_amdgcn_mfma_f32_16x16x32_bf16(Al, Wh[n], acc[mt][n], 0, 0, 0);
      }
    }
  }

  // cross-wave K reduction in LDS (stride 65: 2-way aliasing, free)
  __syncthreads();  // all waves done reading the x tile
  float* red = (float*)smem;
#pragma unroll
  for (int mt = 0; mt < 2; ++mt)
#pragma unroll
    for (int n = 0; n < 4; ++n)
#pragma unroll
      for (int r = 0; r < 4; ++r) {
        const int tokl = mt * 16 + r4 * 4 + r;  // C/D: row = (lane>>4)*4+reg
        const int e = n * 16 + g;               // C/D: col = lane&15
        red[(kq * 32 + tokl) * 65 + e] = acc[mt][n][r];
      }
  __syncthreads();

  // reduce 4 wave-partials -> part[blockIdx][tok*64+e], coalesced float4
  float* pblk = part + (size_t)blockIdx.x * 2048;
#pragma unroll
  for (int i = tid; i < 512; i += 256) {
    const int f = i * 4, tok = f >> 6, e0 = f & 63;
    floatx4 v;
#pragma unroll
    for (int j = 0; j < 4; ++j)
      v[j] = red[(tok) * 65 + e0 + j] + red[(32 + tok) * 65 + e0 + j] +
             red[(64 + tok) * 65 + e0 + j] + red[(96 + tok) * 65 + e0 + j];
    *(floatx4*)(pblk + f) = v;
  }
}

// ---- kernel 2: reduce 4 k-slices + bias -> softmax + top-2 ----
// block = 16 tokens x 16 e-quads (256 threads)
__global__ __launch_bounds__(256) void router_topk(
    const float* __restrict__ part, const float* __restrict__ b,
    float* __restrict__ out, int ntok) {
  const int tid = threadIdx.x;
  const int T = blockIdx.x * 16 + (tid >> 4);
  const int eq = tid & 15, e0 = eq * 4;
  const float* pb = part + ((size_t)(T >> 5) * 4) * 2048 + (T & 31) * 64 + e0;
  floatx4 a = (floatx4){0.f, 0.f, 0.f, 0.f};
#pragma unroll
  for (int s = 0; s < 4; ++s) a += *(const floatx4*)(pb + (size_t)s * 2048);
  floatx4 bb = *(const floatx4*)(b + e0);
  float lv[4];
  float v1 = -INFINITY, v2 = -INFINITY;
  int i1 = 0, i2 = 0;
#pragma unroll
  for (int j = 0; j < 4; ++j) {
    float v = a[j] + bb[j];
    lv[j] = v;
    const int e = e0 + j;
    if (v > v1) { v2 = v1; i2 = i1; v1 = v; i1 = e; }
    else if (v > v2) { v2 = v; i2 = e; }
  }
  // merge top-2 across the 16 e-quad lanes (ties -> lowest index)
#pragma unroll
  for (int off = 1; off < 16; off <<= 1) {
    float ov1 = __shfl_xor(v1, off, 64); int oi1 = __shfl_xor(i1, off, 64);
    float ov2 = __shfl_xor(v2, off, 64); int oi2 = __shfl_xor(i2, off, 64);
    bool aw = (v1 > ov1) || (v1 == ov1 && i1 < oi1);
    float nv1 = aw ? v1 : ov1; int ni1 = aw ? i1 : oi1;
    float c2v = aw ? ov1 : v1; int c2i = aw ? oi1 : i1;
    float w2v = aw ? v2 : ov2; int w2i = aw ? i2 : oi2;
    bool sw = (w2v > c2v) || (w2v == c2v && w2i < c2i);
    v2 = sw ? w2v : c2v; i2 = sw ? w2i : c2i;
    v1 = nv1; i1 = ni1;
  }
  float se = 0.f;
#pragma unroll
  for (int j = 0; j < 4; ++j) se += __expf(lv[j] - v1);
#pragma unroll
  for (int off = 1; off < 16; off <<= 1) se += __shfl_xor(se, off, 64);
  if (eq == 0) {
    out[T * 2 + 0] = (float)i1;
    out[T * 2 + 1] = (float)i2;
    out[ntok * 2 + T * 2 + 0] = 1.0f / se;
    out[ntok * 2 + T * 2 + 1] = __expf(v2 - v1) / se;
  }
}

extern "C" void kernel_launch(void* const* d_in, const int* in_sizes, int n_in,
                              void* d_out, int out_size, void* d_ws, size_t ws_size,
                              hipStream_t stream) {
  const float* x = (const float*)d_in[0];
  const float* W = (const float*)d_in[1];
  const float* b = (const float*)d_in[2];
  float* out = (float*)d_out;
  const int ntok = in_sizes[0] / DIM;          // 16384
  short8* wf = (short8*)d_ws;                  // 512 KB of W fragments
  float* part = (float*)((char*)d_ws + 512 * 1024);  // 16.8 MB partials

  wprep_kernel<<<256, 64, 0, stream>>>(W, wf);
  router_gemm<<<(ntok / 32) * 4, 256, 0, stream>>>(x, wf, part);
  router_topk<<<ntok / 16, 256, 0, stream>>>(part, b, out, ntok);
}

// Round 6
// 200.213 us; speedup vs baseline: 1.0330x; 1.0330x over previous
//
#include <hip/hip_runtime.h>
#include <hip/hip_bf16.h>
#include <math.h>

// Router: logits = x@W + b ; softmax; top-2 -> (idx-as-float, gate)
// x: [16384, 2048] f32, W: [2048, 64] f32, b: [64] f32
// out f32: [ntok*2] indices, then [ntok*2] gates.
//
// R6 theory: rounds 3-5 all streamed x via global_load_lds and all plateaued
// at ~2 TB/s effective fetch. This round removes the LDS-DMA path entirely:
// classic buffer_load->VGPR->ds_write staging, 4 blocks/CU (16 waves/CU) for
// latency hiding. bf16 hi/lo split MFMA (3 products). K-split 4 + reduce pass.

#define DIM 2048
#define NE 64
#define TSTRIDE 2064  // row stride bytes: 512 floats + 16 B pad (16B-aligned)

typedef __attribute__((ext_vector_type(8))) short short8;
typedef __attribute__((ext_vector_type(4))) float floatx4;

__device__ __forceinline__ short bf16bits(float v) {
  __hip_bfloat16 h = __float2bfloat16(v);
  return *(short*)&h;
}
__device__ __forceinline__ float bf16tof(short s) {
  union { unsigned int u; float f; } c;
  c.u = ((unsigned int)(unsigned short)s) << 16;
  return c.f;
}

// ---- W fragment prep: wf[sg(64)][n(4)][plane(2)][lane(64)] = short8 ----
// B-frag 16x16x32: lane l holds B[k = sg*32 + (l>>4)*8 + j][e = n*16 + (l&15)]
__global__ void wprep_kernel(const float* __restrict__ W, short8* __restrict__ wf) {
  const int s = blockIdx.x >> 2, n = blockIdx.x & 3, l = threadIdx.x;
  const int d0 = s * 32 + (l >> 4) * 8;
  const int e = n * 16 + (l & 15);
  short8 vh, vl;
#pragma unroll
  for (int j = 0; j < 8; ++j) {
    float v = W[(size_t)(d0 + j) * NE + e];
    short h = bf16bits(v);
    vh[j] = h;
    vl[j] = bf16bits(v - bf16tof(h));
  }
  wf[(size_t)((s * 4 + n) * 2 + 0) * 64 + l] = vh;
  wf[(size_t)((s * 4 + n) * 2 + 1) * 64 + l] = vl;
}

// ---- kernel 1: partial GEMM. block (g,s): tokens [g*16,+16), k [s*512,+512)
__global__ __launch_bounds__(256, 4) void router_gemm(
    const float* __restrict__ x, const short8* __restrict__ wf,
    float* __restrict__ part) {
  __shared__ alignas(16) char smem[16 * TSTRIDE];  // 33024 B -> 4 blocks/CU
  const int tid = threadIdx.x, lane = tid & 63, kq = tid >> 6;
  const int g = lane & 15, r4 = lane >> 4;
  const int gblk = blockIdx.x >> 2, s = blockIdx.x & 3;
  const int tok0 = gblk * 16;

  // ---- stage 16 rows x 2 KB: wave kq rows [kq*4,+4); lane: row kq*4+r4,
  // 8 x 16 B at col g*16 + p*256. Plain dwordx4 loads -> ds_write_b128.
  {
    const int row = kq * 4 + r4;
    const float* rp = x + (size_t)(tok0 + row) * DIM + s * 512 + g * 4;
    char* wb = smem + row * TSTRIDE + g * 16;
    float4 t[8];
#pragma unroll
    for (int p = 0; p < 8; ++p) t[p] = *(const float4*)(rp + p * 64);
#pragma unroll
    for (int p = 0; p < 8; ++p) *(float4*)(wb + p * 256) = t[p];
  }

  floatx4 acc[4];
#pragma unroll
  for (int n = 0; n < 4; ++n) acc[n] = (floatx4){0.f, 0.f, 0.f, 0.f};

  __syncthreads();

  // wave kq computes k-range [kq*128,+128) of the block's 512-k slice
#pragma unroll
  for (int step = 0; step < 4; ++step) {
    const int sg = s * 16 + kq * 4 + step;  // global 32-k step
    const short8* wp = wf + (size_t)sg * 512;
    short8 Wh[4], Wl[4];
#pragma unroll
    for (int n = 0; n < 4; ++n) {
      Wh[n] = wp[(n * 2 + 0) * 64 + lane];
      Wl[n] = wp[(n * 2 + 1) * 64 + lane];
    }
    // A-frag: m = lane&15 (token), k = step*32 + (lane>>4)*8 + j
    const char* ap = smem + g * TSTRIDE + kq * 512 + step * 128 + r4 * 32;
    floatx4 a0 = *(const floatx4*)ap;
    floatx4 a1 = *(const floatx4*)(ap + 16);
    short8 Ah, Al;
#pragma unroll
    for (int j = 0; j < 4; ++j) {
      short h = bf16bits(a0[j]);
      Ah[j] = h; Al[j] = bf16bits(a0[j] - bf16tof(h));
    }
#pragma unroll
    for (int j = 0; j < 4; ++j) {
      short h = bf16bits(a1[j]);
      Ah[4 + j] = h; Al[4 + j] = bf16bits(a1[j] - bf16tof(h));
    }
#pragma unroll
    for (int n = 0; n < 4; ++n) {
      acc[n] = __builtin_amdgcn_mfma_f32_16x16x32_bf16(Ah, Wh[n], acc[n], 0, 0, 0);
      acc[n] = __builtin_amdgcn_mfma_f32_16x16x32_bf16(Ah, Wl[n], acc[n], 0, 0, 0);
      acc[n] = __builtin_amdgcn_mfma_f32_16x16x32_bf16(Al, Wh[n], acc[n], 0, 0, 0);
    }
  }

  // ---- cross-wave K reduction in LDS (stride 65: 2-way aliasing, free) ----
  __syncthreads();  // all waves done reading the x tile
  float* red = (float*)smem;
#pragma unroll
  for (int n = 0; n < 4; ++n)
#pragma unroll
    for (int r = 0; r < 4; ++r) {
      const int tokl = r4 * 4 + r;  // C/D: row = (lane>>4)*4+reg (token)
      const int e = n * 16 + g;     // C/D: col = lane&15 (expert)
      red[(kq * 16 + tokl) * 65 + e] = acc[n][r];
    }
  __syncthreads();

  // reduce 4 wave-partials -> part[blk][tok*64+e] (1024 B/wave contiguous)
  {
    const int tok = tid >> 4, e0 = (tid & 15) * 4;
    floatx4 v = (floatx4){0.f, 0.f, 0.f, 0.f};
#pragma unroll
    for (int k4 = 0; k4 < 4; ++k4)
#pragma unroll
      for (int j = 0; j < 4; ++j) v[j] += red[(k4 * 16 + tok) * 65 + e0 + j];
    *(floatx4*)(part + (size_t)blockIdx.x * 1024 + tok * 64 + e0) = v;
  }
}

// ---- kernel 2: reduce 4 k-slices + bias -> softmax + top-2 ----
// block = 16 tokens x 16 e-quads (256 threads)
__global__ __launch_bounds__(256) void router_topk(
    const float* __restrict__ part, const float* __restrict__ b,
    float* __restrict__ out, int ntok) {
  const int tid = threadIdx.x;
  const int T = blockIdx.x * 16 + (tid >> 4);
  const int eq = tid & 15, e0 = eq * 4;
  const float* pb = part + (size_t)((T >> 4) * 4) * 1024 + (T & 15) * 64 + e0;
  floatx4 a = (floatx4){0.f, 0.f, 0.f, 0.f};
#pragma unroll
  for (int s = 0; s < 4; ++s) a += *(const floatx4*)(pb + (size_t)s * 1024);
  floatx4 bb = *(const floatx4*)(b + e0);
  float lv[4];
  float v1 = -INFINITY, v2 = -INFINITY;
  int i1 = 0, i2 = 0;
#pragma unroll
  for (int j = 0; j < 4; ++j) {
    float v = a[j] + bb[j];
    lv[j] = v;
    const int e = e0 + j;
    if (v > v1) { v2 = v1; i2 = i1; v1 = v; i1 = e; }
    else if (v > v2) { v2 = v; i2 = e; }
  }
  // merge top-2 across the 16 e-quad lanes (ties -> lowest index)
#pragma unroll
  for (int off = 1; off < 16; off <<= 1) {
    float ov1 = __shfl_xor(v1, off, 64); int oi1 = __shfl_xor(i1, off, 64);
    float ov2 = __shfl_xor(v2, off, 64); int oi2 = __shfl_xor(i2, off, 64);
    bool aw = (v1 > ov1) || (v1 == ov1 && i1 < oi1);
    float nv1 = aw ? v1 : ov1; int ni1 = aw ? i1 : oi1;
    float c2v = aw ? ov1 : v1; int c2i = aw ? oi1 : i1;
    float w2v = aw ? v2 : ov2; int w2i = aw ? i2 : oi2;
    bool sw = (w2v > c2v) || (w2v == c2v && w2i < c2i);
    v2 = sw ? w2v : c2v; i2 = sw ? w2i : c2i;
    v1 = nv1; i1 = ni1;
  }
  float se = 0.f;
#pragma unroll
  for (int j = 0; j < 4; ++j) se += __expf(lv[j] - v1);
#pragma unroll
  for (int off = 1; off < 16; off <<= 1) se += __shfl_xor(se, off, 64);
  if (eq == 0) {
    out[T * 2 + 0] = (float)i1;
    out[T * 2 + 1] = (float)i2;
    out[ntok * 2 + T * 2 + 0] = 1.0f / se;
    out[ntok * 2 + T * 2 + 1] = __expf(v2 - v1) / se;
  }
}

extern "C" void kernel_launch(void* const* d_in, const int* in_sizes, int n_in,
                              void* d_out, int out_size, void* d_ws, size_t ws_size,
                              hipStream_t stream) {
  const float* x = (const float*)d_in[0];
  const float* W = (const float*)d_in[1];
  const float* b = (const float*)d_in[2];
  float* out = (float*)d_out;
  const int ntok = in_sizes[0] / DIM;                // 16384
  short8* wf = (short8*)d_ws;                        // 512 KB W fragments
  float* part = (float*)((char*)d_ws + 512 * 1024);  // 16.8 MB partials

  wprep_kernel<<<256, 64, 0, stream>>>(W, wf);
  router_gemm<<<(ntok / 16) * 4, 256, 0, stream>>>(x, wf, part);
  router_topk<<<ntok / 16, 256, 0, stream>>>(part, b, out, ntok);
}